// Round 1
// baseline (731.458 us; speedup 1.0000x reference)
//
#include <hip/hip_runtime.h>
#include <cstdint>
#include <cstddef>

#define INPUT_DIM 256
#define OUT_DIM   16
#define NMID      784     // middle nodes
#define NNODE     1040
#define KPAD      1056    // effT row length (k dim), multiple of 32
#define SROWS     64      // batch rows per workgroup
#define SSTRIDE   1064    // state row stride (bf16 elems), padded for banks
#define KB        16      // middle-node block size
#define NBLK      49      // 784 / 16

#define STATE_BYTES   (SROWS * SSTRIDE * 2)          // 136192
#define SCR_OFF       STATE_BYTES                     // 4 waves x [16][20] f32
#define WTRI_OFF      (SCR_OFF + 4 * 16 * 20 * 4)    // 141312
#define CST_OFF       (WTRI_OFF + 16 * 16 * 4)       // 142336
#define SMEM_BYTES    (CST_OFF + 16 * 4)             // 142400

typedef float f32x4 __attribute__((ext_vector_type(4)));
typedef __bf16 bf16x8 __attribute__((ext_vector_type(8)));

static __device__ __forceinline__ unsigned short f2bf(float f) {
  unsigned int u = __builtin_bit_cast(unsigned int, f);
  u += 0x7fffu + ((u >> 16) & 1u);   // round-to-nearest-even
  return (unsigned short)(u >> 16);
}
static __device__ __forceinline__ float bf2f(unsigned short h) {
  unsigned int u = ((unsigned int)h) << 16;
  return __builtin_bit_cast(float, u);
}

// ---------------------------------------------------------------------------
// Prep 1: effT[i][j] = w[j][i] * conn[j][i] * ex(j) * (j < 256+i), bf16,
// layout [NMID][KPAD] (k-major rows), zero-padded. LDS tile transpose.
// ---------------------------------------------------------------------------
__global__ __launch_bounds__(256) void prep_efft(
    const float* __restrict__ w, const int* __restrict__ conn,
    const int* __restrict__ ex, unsigned short* __restrict__ effT) {
  __shared__ unsigned short tile[64][66];
  const int j0 = blockIdx.x * 64;
  const int i0 = blockIdx.y * 64;
  const int tx = threadIdx.x & 63;   // i offset
  const int ty = threadIdx.x >> 6;   // j sub-row
  const int i  = i0 + tx;
  for (int t = 0; t < 16; ++t) {
    int j = j0 + t * 4 + ty;
    float v = 0.f;
    if (j < NNODE && i < NMID && j < INPUT_DIM + i) {
      float e = (j >= INPUT_DIM) ? (float)ex[j - INPUT_DIM] : 1.f;
      v = w[(size_t)j * NMID + i] * (float)conn[(size_t)j * NMID + i] * e;
    }
    tile[t * 4 + ty][tx] = f2bf(v);
  }
  __syncthreads();
  const int i_loc = threadIdx.x >> 2;
  const int jq    = threadIdx.x & 3;
  const int iw    = i0 + i_loc;
  const int jbase = j0 + jq * 16;
  if (iw < NMID && jbase + 16 <= KPAD) {
    #pragma unroll
    for (int c = 0; c < 16; ++c)
      effT[(size_t)iw * KPAD + jbase + c] = tile[jq * 16 + c][i_loc];
  }
}

// ---------------------------------------------------------------------------
// Prep 2: cvec[i] = sum_j effT[i][256+j] * bias[j]   (bias folded constant)
// ---------------------------------------------------------------------------
__global__ __launch_bounds__(64) void prep_cvec(
    const unsigned short* __restrict__ effT, const float* __restrict__ bias,
    float* __restrict__ cvec) {
  const int i = blockIdx.x;
  const int l = threadIdx.x;
  float s = 0.f;
  for (int jj = l; jj < NMID; jj += 64)
    s += bf2f(effT[(size_t)i * KPAD + INPUT_DIM + jj]) * bias[jj];
  for (int off = 32; off; off >>= 1) s += __shfl_down(s, off, 64);
  if (l == 0) cvec[i] = s;
}

// ---------------------------------------------------------------------------
// Main: per-wg 64-row batch tile; state in LDS bf16; 49 blocks of 16 nodes:
//   GEMM (MFMA over prior nodes) -> transpose -> in-register triangular solve
// ---------------------------------------------------------------------------
__global__ __launch_bounds__(256, 1) void net_main(
    const float* __restrict__ x, const unsigned short* __restrict__ effT,
    const float* __restrict__ cvec, const float* __restrict__ bias,
    const int* __restrict__ ex, float* __restrict__ out) {
  extern __shared__ char smem[];
  unsigned short* state = (unsigned short*)smem;         // [64][SSTRIDE] bf16
  float* scratch = (float*)(smem + SCR_OFF);             // 4 x [16][20] f32
  float* wtri    = (float*)(smem + WTRI_OFF);            // [16][16] f32
  float* cst     = (float*)(smem + CST_OFF);             // [16] f32

  const int tid = threadIdx.x;
  const int l   = tid & 63;
  const int wv  = tid >> 6;
  const int g   = l >> 4;           // lane quad-group
  const int r16 = l & 15;
  const int r0  = blockIdx.x * SROWS;
  const int rowA = 16 * wv + r16;   // this lane's batch row (local)

  // zero entire state (incl. padding)
  {
    uint4 z; z.x = z.y = z.z = z.w = 0u;
    for (int i = tid; i < STATE_BYTES / 16; i += 256) ((uint4*)smem)[i] = z;
  }
  __syncthreads();

  // load x -> bf16 state[:, 0:256]  (fully coalesced float4 reads)
  for (int p = 0; p < 16; ++p) {
    int flat = p * 1024 + tid * 4;            // elem index in [64][256]
    int row  = flat >> 8;
    int col  = flat & 255;
    float4 v = *(const float4*)(x + (size_t)(r0 + row) * INPUT_DIM + col);
    uint2 u;
    u.x = (unsigned int)f2bf(v.x) | ((unsigned int)f2bf(v.y) << 16);
    u.y = (unsigned int)f2bf(v.z) | ((unsigned int)f2bf(v.w) << 16);
    *(uint2*)(state + (size_t)row * SSTRIDE + col) = u;
  }
  __syncthreads();

  float* myscr = scratch + wv * 320;          // [16][20]

  for (int b = 0; b < NBLK; ++b) {
    // ---- stage wtri (in-block weights, f32) + cst ----
    {
      int k = tid & 15, c = tid >> 4;         // 256 threads cover 16x16
      wtri[k * 16 + c] =
          bf2f(effT[(size_t)(KB * b + c) * KPAD + (INPUT_DIM + KB * b + k)]);
      if (tid < 16) cst[tid] = cvec[KB * b + tid];
    }
    __syncthreads();

    // ---- GEMM: C[16 rows x 16 cols] over all prior k (chunk-rounded; the
    //      current block's state is still zero, so extra chunks add 0) ----
    f32x4 acc = {0.f, 0.f, 0.f, 0.f};
    const int nch = 8 + ((16 * b + 31) >> 5);
    const unsigned short* bptr =
        effT + (size_t)(KB * b + r16) * KPAD + 8 * (l >> 4);
    const unsigned short* aptr = state + (size_t)rowA * SSTRIDE + 8 * (l >> 4);
    #pragma unroll 4
    for (int c = 0; c < nch; ++c) {
      uint4 araw = *(const uint4*)(aptr + 32 * c);
      uint4 braw = *(const uint4*)(bptr + 32 * c);
      acc = __builtin_amdgcn_mfma_f32_16x16x32_bf16(
          __builtin_bit_cast(bf16x8, araw), __builtin_bit_cast(bf16x8, braw),
          acc, 0, 0, 0);
    }

    // ---- transpose: lane ends with its row's 16 column accumulators ----
    // C layout: col = l&15, row = 4*(l>>4)+i  -> scr[row][col]
    #pragma unroll
    for (int i = 0; i < 4; ++i)
      myscr[(4 * g + i) * 20 + r16] = acc[i];
    // same-wave LDS ops are in-order; float->float alias keeps program order
    float acc_t[16];
    #pragma unroll
    for (int c = 0; c < 16; ++c)
      acc_t[c] = myscr[r16 * 20 + c] + cst[c];

    // ---- triangular phase (redundant across the 4 lane-quads) ----
    float vals[16];
    #pragma unroll
    for (int k = 0; k < 16; ++k) {
      float xk = acc_t[k];
      float s  = __builtin_amdgcn_rcpf(
          1.f + __builtin_amdgcn_exp2f(xk * -1.44269504088896341f));
      vals[k] = s;
      const float4* wrow = (const float4*)(wtri + k * 16);
      float4 w0 = wrow[0], w1 = wrow[1], w2 = wrow[2], w3 = wrow[3];
      float wr[16] = {w0.x, w0.y, w0.z, w0.w, w1.x, w1.y, w1.z, w1.w,
                      w2.x, w2.y, w2.z, w2.w, w3.x, w3.y, w3.z, w3.w};
      #pragma unroll
      for (int c = k + 1; c < 16; ++c) acc_t[c] += s * wr[c];
    }

    // ---- writeback: lane writes cols 4g..4g+3 of its row as bf16 ----
    {
      int cb = 4 * g;
      uint2 u;
      u.x = (unsigned int)f2bf(vals[cb])     | ((unsigned int)f2bf(vals[cb + 1]) << 16);
      u.y = (unsigned int)f2bf(vals[cb + 2]) | ((unsigned int)f2bf(vals[cb + 3]) << 16);
      *(uint2*)(state + (size_t)rowA * SSTRIDE + (INPUT_DIM + KB * b + cb)) = u;
    }
    if (b == NBLK - 1) {
      // output nodes are exactly this block: out = (sig + bias)*ex
      const size_t grow = (size_t)(r0 + rowA) * OUT_DIM;
      #pragma unroll
      for (int i = 0; i < 4; ++i) {
        int oc = 4 * g + i;
        float e  = (float)ex[NMID - OUT_DIM + oc];
        float bo = bias[NMID - OUT_DIM + oc];
        out[grow + oc] = (vals[oc] + bo) * e;
      }
    }
    __syncthreads();
  }
}

// ---------------------------------------------------------------------------
extern "C" void kernel_launch(void* const* d_in, const int* in_sizes, int n_in,
                              void* d_out, int out_size, void* d_ws, size_t ws_size,
                              hipStream_t stream) {
  const float* x      = (const float*)d_in[0];
  const float* weight = (const float*)d_in[1];
  const float* bias   = (const float*)d_in[2];
  const int*   conn   = (const int*)d_in[3];
  const int*   ex     = (const int*)d_in[4];

  unsigned short* effT = (unsigned short*)d_ws;                 // 784*1056*2 B
  float* cvec = (float*)((char*)d_ws + (size_t)NMID * KPAD * 2);

  hipFuncSetAttribute(reinterpret_cast<const void*>(net_main),
                      hipFuncAttributeMaxDynamicSharedMemorySize, SMEM_BYTES);

  prep_efft<<<dim3(17, 13), 256, 0, stream>>>(weight, conn, ex, effT);
  prep_cvec<<<dim3(NMID), 64, 0, stream>>>(effT, bias, cvec);
  net_main<<<dim3(32768 / SROWS), 256, SMEM_BYTES, stream>>>(
      x, effT, cvec, bias, ex, (float*)d_out);
}

// Round 2
// 451.829 us; speedup vs baseline: 1.6189x; 1.6189x over previous
//
#include <hip/hip_runtime.h>
#include <cstdint>
#include <cstddef>

#define INPUT_DIM 256
#define OUT_DIM   16
#define NMID      784     // middle nodes
#define NNODE     1040
#define KPAD      1056    // effT row length (k dim), multiple of 32
#define KB        16      // middle-node block size
#define NBLK      49      // 784 / 16
#define NCHMAX    32      // state chunks of 32 k-elems (k < 1024 read max)

typedef float f32x4 __attribute__((ext_vector_type(4)));
typedef __bf16 bf16x8 __attribute__((ext_vector_type(8)));

static __device__ __forceinline__ unsigned int f2bf(float f) {
  unsigned int u = __builtin_bit_cast(unsigned int, f);
  u += 0x7fffu + ((u >> 16) & 1u);   // round-to-nearest-even
  return u >> 16;
}
static __device__ __forceinline__ float bf2f(unsigned short h) {
  unsigned int u = ((unsigned int)h) << 16;
  return __builtin_bit_cast(float, u);
}

// ---------------------------------------------------------------------------
// Prep 1: effT[i][j] = w[j][i] * conn[j][i] * ex(j) * (j < 256+i), bf16,
// layout [NMID][KPAD] (k-major rows), zero-padded. LDS tile transpose.
// ---------------------------------------------------------------------------
__global__ __launch_bounds__(256) void prep_efft(
    const float* __restrict__ w, const int* __restrict__ conn,
    const int* __restrict__ ex, unsigned short* __restrict__ effT) {
  __shared__ unsigned short tile[64][66];
  const int j0 = blockIdx.x * 64;
  const int i0 = blockIdx.y * 64;
  const int tx = threadIdx.x & 63;   // i offset
  const int ty = threadIdx.x >> 6;   // j sub-row
  const int i  = i0 + tx;
  for (int t = 0; t < 16; ++t) {
    int j = j0 + t * 4 + ty;
    float v = 0.f;
    if (j < NNODE && i < NMID && j < INPUT_DIM + i) {
      float e = (j >= INPUT_DIM) ? (float)ex[j - INPUT_DIM] : 1.f;
      v = w[(size_t)j * NMID + i] * (float)conn[(size_t)j * NMID + i] * e;
    }
    tile[t * 4 + ty][tx] = (unsigned short)f2bf(v);
  }
  __syncthreads();
  const int i_loc = threadIdx.x >> 2;
  const int jq    = threadIdx.x & 3;
  const int iw    = i0 + i_loc;
  const int jbase = j0 + jq * 16;
  if (iw < NMID && jbase + 16 <= KPAD) {
    #pragma unroll
    for (int c = 0; c < 16; ++c)
      effT[(size_t)iw * KPAD + jbase + c] = tile[jq * 16 + c][i_loc];
  }
}

// ---------------------------------------------------------------------------
// Prep 2: cvec[i] = sum_j effT[i][256+j] * bias[j]   (bias folded constant)
// ---------------------------------------------------------------------------
__global__ __launch_bounds__(64) void prep_cvec(
    const unsigned short* __restrict__ effT, const float* __restrict__ bias,
    float* __restrict__ cvec) {
  const int i = blockIdx.x;
  const int l = threadIdx.x;
  float s = 0.f;
  for (int jj = l; jj < NMID; jj += 64)
    s += bf2f(effT[(size_t)i * KPAD + INPUT_DIM + jj]) * bias[jj];
  for (int off = 32; off; off >>= 1) s += __shfl_down(s, off, 64);
  if (l == 0) cvec[i] = s;
}

// ---------------------------------------------------------------------------
// Prep 3: wpack[b][k][c] = w[256+16b+k][16b+c]*conn*ex[16b+k]*(k<c)  (f32)
// In-block triangular weights, contiguous 1 KB per block.
// ---------------------------------------------------------------------------
__global__ __launch_bounds__(256) void prep_wpack(
    const float* __restrict__ w, const int* __restrict__ conn,
    const int* __restrict__ ex, float* __restrict__ wpack) {
  const int b = blockIdx.x;
  const int k = threadIdx.x >> 4;   // source node within block
  const int c = threadIdx.x & 15;   // dest node within block
  const int src = KB * b + k;       // middle idx
  const int dst = KB * b + c;
  float v = 0.f;
  if (k < c) {
    size_t idx = (size_t)(INPUT_DIM + src) * NMID + dst;
    v = w[idx] * (float)conn[idx] * (float)ex[src];
  }
  wpack[b * 256 + k * 16 + c] = v;
}

// ---------------------------------------------------------------------------
// Main: one wave = 16 batch rows, fully independent (no __syncthreads).
// Whole state row in registers in MFMA-A fragment layout: uint4 sfrag[32],
// chunk c holds bf16 state[row=l&15][k = 32c + 8*(l>>4) .. +7].
// Per block: guarded-unrolled MFMA over prior chunks -> LDS 16x16 transpose
// (per-wave scratch) -> in-register triangular solve -> pack result straight
// into the owning fragment register.
// ---------------------------------------------------------------------------
__global__ __launch_bounds__(256, 2) void net_main(
    const float* __restrict__ x, const unsigned short* __restrict__ effT,
    const float* __restrict__ cvec, const float* __restrict__ wpack,
    const float* __restrict__ bias, const int* __restrict__ ex,
    float* __restrict__ out) {
  __shared__ float wtriS[4][256];   // per-wave in-block weights [k][c]
  __shared__ float scrS[4][320];    // per-wave 16x20 transpose scratch

  const int tid = threadIdx.x;
  const int l   = tid & 63;
  const int wv  = tid >> 6;
  const int g   = l >> 4;
  const int r16 = l & 15;
  const int grow = (blockIdx.x * 4 + wv) * 16 + r16;  // global batch row

  float* wtri  = wtriS[wv];
  float* myscr = scrS[wv];

  uint4 sfrag[NCHMAX];
  // chunks 0..7 <- x (f32 -> bf16), fragment layout
  #pragma unroll
  for (int c = 0; c < 8; ++c) {
    const float* p = x + (size_t)grow * INPUT_DIM + 32 * c + 8 * g;
    float4 v0 = *(const float4*)p;
    float4 v1 = *(const float4*)(p + 4);
    uint4 u;
    u.x = f2bf(v0.x) | (f2bf(v0.y) << 16);
    u.y = f2bf(v0.z) | (f2bf(v0.w) << 16);
    u.z = f2bf(v1.x) | (f2bf(v1.y) << 16);
    u.w = f2bf(v1.z) | (f2bf(v1.w) << 16);
    sfrag[c] = u;
  }
  #pragma unroll
  for (int c = 8; c < NCHMAX; ++c) {
    uint4 z; z.x = z.y = z.z = z.w = 0u;
    sfrag[c] = z;
  }

  for (int b = 0; b < NBLK; ++b) {
    // ---- stage in-block weights: 1 KB coalesced, per-wave LDS ----
    *(float4*)(wtri + 4 * l) = *(const float4*)(wpack + b * 256 + 4 * l);

    // ---- GEMM over prior chunks (guarded full unroll; acc striped x4) ----
    f32x4 ac0 = {0.f,0.f,0.f,0.f}, ac1 = ac0, ac2 = ac0, ac3 = ac0;
    const unsigned short* bbase =
        effT + (size_t)(KB * b + r16) * KPAD + 8 * g;
    const int nch = 8 + ((b + 1) >> 1);   // ceil((256+16b)/32)
    #pragma unroll
    for (int c = 0; c < 8; ++c) {
      uint4 braw = *(const uint4*)(bbase + 32 * c);
      f32x4& a = (c & 3) == 0 ? ac0 : (c & 3) == 1 ? ac1 : (c & 3) == 2 ? ac2 : ac3;
      a = __builtin_amdgcn_mfma_f32_16x16x32_bf16(
          __builtin_bit_cast(bf16x8, sfrag[c]), __builtin_bit_cast(bf16x8, braw),
          a, 0, 0, 0);
    }
    #pragma unroll
    for (int c = 8; c < NCHMAX; ++c) {
      if (c < nch) {
        uint4 braw = *(const uint4*)(bbase + 32 * c);
        f32x4& a = (c & 3) == 0 ? ac0 : (c & 3) == 1 ? ac1 : (c & 3) == 2 ? ac2 : ac3;
        a = __builtin_amdgcn_mfma_f32_16x16x32_bf16(
            __builtin_bit_cast(bf16x8, sfrag[c]), __builtin_bit_cast(bf16x8, braw),
            a, 0, 0, 0);
      }
    }
    f32x4 accsum = (ac0 + ac1) + (ac2 + ac3);

    // ---- transpose via per-wave LDS scratch (C-layout -> row-per-lane) ----
    #pragma unroll
    for (int i = 0; i < 4; ++i)
      myscr[(4 * g + i) * 20 + r16] = accsum[i];
    float acc_t[16];
    #pragma unroll
    for (int c = 0; c < 16; ++c)
      acc_t[c] = myscr[r16 * 20 + c];

    // ---- triangular phase (redundant across the 4 lane-groups) ----
    #pragma unroll
    for (int k = 0; k < 16; ++k) {
      float xk = acc_t[k] + cvec[KB * b + k];     // uniform scalar load
      float s  = __builtin_amdgcn_rcpf(
          1.f + __builtin_amdgcn_exp2f(xk * -1.44269504088896341f));
      acc_t[k] = s;                               // reuse slot as value store
      const float4* wrow = (const float4*)(wtri + k * 16);
      float4 w0 = wrow[0], w1 = wrow[1], w2 = wrow[2], w3 = wrow[3];
      float wr[16] = {w0.x, w0.y, w0.z, w0.w, w1.x, w1.y, w1.z, w1.w,
                      w2.x, w2.y, w2.z, w2.w, w3.x, w3.y, w3.z, w3.w};
      #pragma unroll
      for (int c = k + 1; c < 16; ++c) acc_t[c] += s * wr[c];
    }

    if (b == NBLK - 1) {
      // output nodes = this block: out = (sig + bias)*ex
      #pragma unroll
      for (int i = 0; i < 4; ++i) {
        int oc = 4 * g + i;
        int mi = NMID - OUT_DIM + oc;
        out[(size_t)grow * OUT_DIM + oc] =
            (acc_t[oc] + bias[mi]) * (float)ex[mi];
      }
    } else {
      // pack the 16 new node values straight into the owning fragment reg.
      // New cols k in [256+16b, +16): chunk cw = 8+(b>>1), intra-chunk offset
      // (b&1)*16 -> lane-groups g with (g>>1)==(b&1); block-col = 8*(g&1)+j.
      const int cw = 8 + (b >> 1);
      const int vb = 8 * (g & 1);
      uint4 packed;
      packed.x = f2bf(acc_t[vb + 0]) | (f2bf(acc_t[vb + 1]) << 16);
      packed.y = f2bf(acc_t[vb + 2]) | (f2bf(acc_t[vb + 3]) << 16);
      packed.z = f2bf(acc_t[vb + 4]) | (f2bf(acc_t[vb + 5]) << 16);
      packed.w = f2bf(acc_t[vb + 6]) | (f2bf(acc_t[vb + 7]) << 16);
      const bool part = ((g >> 1) == (b & 1));
      #pragma unroll
      for (int c = 8; c < NCHMAX; ++c) {
        if (c == cw) {                 // uniform guard -> static reg index
          if (part) sfrag[c] = packed; // lane-divergent select
        }
      }
    }
  }
}

// ---------------------------------------------------------------------------
extern "C" void kernel_launch(void* const* d_in, const int* in_sizes, int n_in,
                              void* d_out, int out_size, void* d_ws, size_t ws_size,
                              hipStream_t stream) {
  const float* x      = (const float*)d_in[0];
  const float* weight = (const float*)d_in[1];
  const float* bias   = (const float*)d_in[2];
  const int*   conn   = (const int*)d_in[3];
  const int*   ex     = (const int*)d_in[4];

  unsigned short* effT = (unsigned short*)d_ws;                  // 784*1056*2
  float* cvec  = (float*)((char*)d_ws + (size_t)NMID * KPAD * 2);
  float* wpack = (float*)((char*)d_ws + (size_t)NMID * KPAD * 2 + NMID * 4);

  prep_efft<<<dim3(17, 13), 256, 0, stream>>>(weight, conn, ex, effT);
  prep_cvec<<<dim3(NMID), 64, 0, stream>>>(effT, bias, cvec);
  prep_wpack<<<dim3(NBLK), 256, 0, stream>>>(weight, conn, ex, wpack);
  net_main<<<dim3(32768 / 64), 256, 0, stream>>>(
      x, effT, cvec, wpack, bias, ex, (float*)d_out);
}

// Round 3
// 223.884 us; speedup vs baseline: 3.2671x; 2.0181x over previous
//
#include <hip/hip_runtime.h>
#include <cstdint>
#include <cstddef>

#define INPUT_DIM 256
#define OUT_DIM   16
#define NMID      784     // middle nodes
#define NNODE     1040
#define KPAD      1056    // effT row length (k dim), multiple of 32
#define KB        16      // middle-node block size
#define NBLK      49      // 784 / 16
#define NCHMAX    32      // state chunks of 32 k-elems
#define LROW      1032    // LDS B row stride in bf16 elems (2064 B)

typedef float f32x4 __attribute__((ext_vector_type(4)));
typedef __bf16 bf16x8 __attribute__((ext_vector_type(8)));

#define GLL16(gp, lp)                                                        \
  __builtin_amdgcn_global_load_lds(                                          \
      (const __attribute__((address_space(1))) unsigned int*)(gp),           \
      (__attribute__((address_space(3))) unsigned int*)(lp), 16, 0, 0)

static __device__ __forceinline__ unsigned int f2bf(float f) {
  unsigned int u = __builtin_bit_cast(unsigned int, f);
  u += 0x7fffu + ((u >> 16) & 1u);   // round-to-nearest-even
  return u >> 16;
}
static __device__ __forceinline__ float bf2f(unsigned short h) {
  unsigned int u = ((unsigned int)h) << 16;
  return __builtin_bit_cast(float, u);
}

// ---------------------------------------------------------------------------
// Prep 1: effT[i][j] = w[j][i] * conn[j][i] * ex(j) * (j < 256+i), bf16,
// layout [NMID][KPAD] (k-major rows), zero-padded. LDS tile transpose.
// ---------------------------------------------------------------------------
__global__ __launch_bounds__(256) void prep_efft(
    const float* __restrict__ w, const int* __restrict__ conn,
    const int* __restrict__ ex, unsigned short* __restrict__ effT) {
  __shared__ unsigned short tile[64][66];
  const int j0 = blockIdx.x * 64;
  const int i0 = blockIdx.y * 64;
  const int tx = threadIdx.x & 63;   // i offset
  const int ty = threadIdx.x >> 6;   // j sub-row
  const int i  = i0 + tx;
  for (int t = 0; t < 16; ++t) {
    int j = j0 + t * 4 + ty;
    float v = 0.f;
    if (j < NNODE && i < NMID && j < INPUT_DIM + i) {
      float e = (j >= INPUT_DIM) ? (float)ex[j - INPUT_DIM] : 1.f;
      v = w[(size_t)j * NMID + i] * (float)conn[(size_t)j * NMID + i] * e;
    }
    tile[t * 4 + ty][tx] = (unsigned short)f2bf(v);
  }
  __syncthreads();
  const int i_loc = threadIdx.x >> 2;
  const int jq    = threadIdx.x & 3;
  const int iw    = i0 + i_loc;
  const int jbase = j0 + jq * 16;
  if (iw < NMID && jbase + 16 <= KPAD) {
    #pragma unroll
    for (int c = 0; c < 16; ++c)
      effT[(size_t)iw * KPAD + jbase + c] = tile[jq * 16 + c][i_loc];
  }
}

// ---------------------------------------------------------------------------
// Prep 2: cvec[i] = sum_j effT[i][256+j] * bias[j]   (bias folded constant)
// ---------------------------------------------------------------------------
__global__ __launch_bounds__(64) void prep_cvec(
    const unsigned short* __restrict__ effT, const float* __restrict__ bias,
    float* __restrict__ cvec) {
  const int i = blockIdx.x;
  const int l = threadIdx.x;
  float s = 0.f;
  for (int jj = l; jj < NMID; jj += 64)
    s += bf2f(effT[(size_t)i * KPAD + INPUT_DIM + jj]) * bias[jj];
  for (int off = 32; off; off >>= 1) s += __shfl_down(s, off, 64);
  if (l == 0) cvec[i] = s;
}

// ---------------------------------------------------------------------------
// Prep 3: wpack[b][k][c] = w[256+16b+k][16b+c]*conn*ex[16b+k]*(k<c)  (f32)
// ---------------------------------------------------------------------------
__global__ __launch_bounds__(256) void prep_wpack(
    const float* __restrict__ w, const int* __restrict__ conn,
    const int* __restrict__ ex, float* __restrict__ wpack) {
  const int b = blockIdx.x;
  const int k = threadIdx.x >> 4;   // source node within block
  const int c = threadIdx.x & 15;   // dest node within block
  const int src = KB * b + k;
  const int dst = KB * b + c;
  float v = 0.f;
  if (k < c) {
    size_t idx = (size_t)(INPUT_DIM + src) * NMID + dst;
    v = w[idx] * (float)conn[idx] * (float)ex[src];
  }
  wpack[b * 256 + k * 16 + c] = v;
}

// ---------------------------------------------------------------------------
// Main: wave = 16 batch rows; state in MFMA-A fragment regs (uint4 sfrag[32]).
// Per block: B staged in shared LDS (double-buffered, global_load_lds) ->
// 4 straight-line 8-chunk MFMA phases -> LDS transpose -> in-reg triangular
// solve -> pack into owning fragment reg. One barrier per block.
// ---------------------------------------------------------------------------
__global__ __launch_bounds__(256, 2) void net_main(
    const float* __restrict__ x, const unsigned short* __restrict__ effT,
    const float* __restrict__ cvec, const float* __restrict__ wpack,
    const float* __restrict__ bias, const int* __restrict__ ex,
    float* __restrict__ out) {
  __shared__ unsigned short Bs[2][16 * LROW];   // 66048 B
  __shared__ float wtri2[2][256];               // 2048 B
  __shared__ float scrS[4][320];                // 5120 B

  const int tid = threadIdx.x;
  const int l   = tid & 63;
  const int wv  = tid >> 6;
  const int g   = l >> 4;
  const int r16 = l & 15;
  const int grow = (blockIdx.x * 4 + wv) * 16 + r16;  // global batch row

  float* myscr = scrS[wv];

  // ---- state: chunks 0..7 <- x (f32 -> bf16), rest zero ----
  uint4 sfrag[NCHMAX];
  #pragma unroll
  for (int c = 0; c < 8; ++c) {
    const float* p = x + (size_t)grow * INPUT_DIM + 32 * c + 8 * g;
    float4 v0 = *(const float4*)p;
    float4 v1 = *(const float4*)(p + 4);
    uint4 u;
    u.x = f2bf(v0.x) | (f2bf(v0.y) << 16);
    u.y = f2bf(v0.z) | (f2bf(v0.w) << 16);
    u.z = f2bf(v1.x) | (f2bf(v1.y) << 16);
    u.w = f2bf(v1.z) | (f2bf(v1.w) << 16);
    sfrag[c] = u;
  }
  #pragma unroll
  for (int c = 8; c < NCHMAX; ++c) {
    uint4 z; z.x = z.y = z.z = z.w = 0u;
    sfrag[c] = z;
  }

  // ---- staging helpers (macros to keep literals literal) ----
  // stage B rows of block t into buffer nb: wave wv rows 4wv..4wv+3, 2 KB each
#define STAGE_B(nb, t)                                                        \
  {                                                                           \
    _Pragma("unroll")                                                         \
    for (int k_ = 0; k_ < 4; ++k_) {                                          \
      const int r_ = 4 * wv + k_;                                             \
      const char* gsrc_ =                                                     \
          (const char*)(effT + (size_t)(16 * (t) + r_) * KPAD) + l * 16;      \
      unsigned short* ldst_ = &Bs[nb][r_ * LROW];                             \
      GLL16(gsrc_, ldst_);                                                    \
      GLL16(gsrc_ + 1024, (char*)ldst_ + 1024);                               \
    }                                                                         \
  }
#define STAGE_W(nb, t)                                                        \
  if (l < 16) {                                                               \
    *(float4*)&wtri2[nb][wv * 64 + 4 * l] =                                   \
        *(const float4*)&wpack[(t) * 256 + wv * 64 + 4 * l];                  \
  }

  // ---- prologue: stage block 0 ----
  STAGE_B(0, 0);
  STAGE_W(0, 0);
  __syncthreads();   // drains vmcnt -> Bs[0]/wtri2[0] ready

  for (int b = 0; b < NBLK; ++b) {
    const int cur = b & 1;

    // issue next block's staging first; latency hides under GEMM+solve
    if (b + 1 < NBLK) {
      STAGE_B(cur ^ 1, b + 1);
      STAGE_W(cur ^ 1, b + 1);
    }

    // ---- GEMM: 4 straight-line phases of 8 chunks (extra chunks add 0) ----
    f32x4 ac0 = {0.f,0.f,0.f,0.f}, ac1 = ac0, ac2 = ac0, ac3 = ac0;
    const unsigned short* bb = &Bs[cur][r16 * LROW + g * 8];
#define CHUNK(c)                                                              \
  {                                                                           \
    uint4 braw = *(const uint4*)(bb + (c) * 32);                              \
    f32x4& a_ = ((c) & 3) == 0 ? ac0 : ((c) & 3) == 1 ? ac1                   \
               : ((c) & 3) == 2 ? ac2 : ac3;                                  \
    a_ = __builtin_amdgcn_mfma_f32_16x16x32_bf16(                             \
        __builtin_bit_cast(bf16x8, sfrag[(c)]),                               \
        __builtin_bit_cast(bf16x8, braw), a_, 0, 0, 0);                       \
  }
    CHUNK(0) CHUNK(1) CHUNK(2) CHUNK(3) CHUNK(4) CHUNK(5) CHUNK(6) CHUNK(7)
    if (b >= 1) {
      CHUNK(8) CHUNK(9) CHUNK(10) CHUNK(11)
      CHUNK(12) CHUNK(13) CHUNK(14) CHUNK(15)
    }
    if (b >= 17) {
      CHUNK(16) CHUNK(17) CHUNK(18) CHUNK(19)
      CHUNK(20) CHUNK(21) CHUNK(22) CHUNK(23)
    }
    if (b >= 33) {
      CHUNK(24) CHUNK(25) CHUNK(26) CHUNK(27)
      CHUNK(28) CHUNK(29) CHUNK(30) CHUNK(31)
    }
#undef CHUNK
    f32x4 accsum = (ac0 + ac1) + (ac2 + ac3);

    // ---- transpose via per-wave LDS scratch (C-layout -> row-per-lane) ----
    #pragma unroll
    for (int i = 0; i < 4; ++i)
      myscr[(4 * g + i) * 20 + r16] = accsum[i];
    float acc_t[16];
    #pragma unroll
    for (int c = 0; c < 16; ++c)
      acc_t[c] = myscr[r16 * 20 + c];

    // ---- triangular phase (redundant across the 4 lane-groups) ----
    const float* wtri = wtri2[cur];
    #pragma unroll
    for (int k = 0; k < 16; ++k) {
      float xk = acc_t[k] + cvec[KB * b + k];     // uniform scalar load
      float s  = __builtin_amdgcn_rcpf(
          1.f + __builtin_amdgcn_exp2f(xk * -1.44269504088896341f));
      acc_t[k] = s;
      const float4* wrow = (const float4*)(wtri + k * 16);
      float4 w0 = wrow[0], w1 = wrow[1], w2 = wrow[2], w3 = wrow[3];
      float wr[16] = {w0.x, w0.y, w0.z, w0.w, w1.x, w1.y, w1.z, w1.w,
                      w2.x, w2.y, w2.z, w2.w, w3.x, w3.y, w3.z, w3.w};
      #pragma unroll
      for (int c = k + 1; c < 16; ++c) acc_t[c] += s * wr[c];
    }

    if (b == NBLK - 1) {
      #pragma unroll
      for (int i = 0; i < 4; ++i) {
        int oc = 4 * g + i;
        int mi = NMID - OUT_DIM + oc;
        out[(size_t)grow * OUT_DIM + oc] =
            (acc_t[oc] + bias[mi]) * (float)ex[mi];
      }
    } else {
      // pack 16 new node values straight into the owning fragment register
      const int cw = 8 + (b >> 1);
      const int vb = 8 * (g & 1);
      uint4 packed;
      packed.x = f2bf(acc_t[vb + 0]) | (f2bf(acc_t[vb + 1]) << 16);
      packed.y = f2bf(acc_t[vb + 2]) | (f2bf(acc_t[vb + 3]) << 16);
      packed.z = f2bf(acc_t[vb + 4]) | (f2bf(acc_t[vb + 5]) << 16);
      packed.w = f2bf(acc_t[vb + 6]) | (f2bf(acc_t[vb + 7]) << 16);
      const bool part = ((g >> 1) == (b & 1));
      #pragma unroll
      for (int c = 8; c < NCHMAX; ++c) {
        if (c == cw) {
          if (part) sfrag[c] = packed;
        }
      }
    }

    __syncthreads();   // next block's staged B/wtri ready; prior reads done
  }
#undef STAGE_B
#undef STAGE_W
}

// ---------------------------------------------------------------------------
extern "C" void kernel_launch(void* const* d_in, const int* in_sizes, int n_in,
                              void* d_out, int out_size, void* d_ws, size_t ws_size,
                              hipStream_t stream) {
  const float* x      = (const float*)d_in[0];
  const float* weight = (const float*)d_in[1];
  const float* bias   = (const float*)d_in[2];
  const int*   conn   = (const int*)d_in[3];
  const int*   ex     = (const int*)d_in[4];

  unsigned short* effT = (unsigned short*)d_ws;                  // 784*1056*2
  float* cvec  = (float*)((char*)d_ws + (size_t)NMID * KPAD * 2);
  float* wpack = (float*)((char*)d_ws + (size_t)NMID * KPAD * 2 + NMID * 4);

  prep_efft<<<dim3(17, 13), 256, 0, stream>>>(weight, conn, ex, effT);
  prep_cvec<<<dim3(NMID), 64, 0, stream>>>(effT, bias, cvec);
  prep_wpack<<<dim3(NBLK), 256, 0, stream>>>(weight, conn, ex, wpack);
  net_main<<<dim3(32768 / 64), 256, 0, stream>>>(
      x, effT, cvec, wpack, bias, ex, (float*)d_out);
}